// Round 2
// baseline (2905.506 us; speedup 1.0000x reference)
//
#include <hip/hip_runtime.h>
#include <math.h>

// Problem constants (fixed by the reference)
#define HDIM   512
#define NDIM   16
#define SEQ    64
#define TSTEPS 63
#define BATCH  256
#define ODIM   9
#define NTHR   512
#define GSTR   132   // bank-padded row stride for ld_g (spreads gelu writes)
#define SPIN_CAP (1 << 24)   // ~0.45s of s_sleep(1): converts deadlock -> wrong-answer diag

// R9 == R8 design, hardened (R8 never ran: container failed twice; all spin
// loops now bounded so a protocol failure surfaces as passed:false + counters
// instead of a dead container).
//
// R8: ONE rendezvous per S4 block (2/step instead of 4). Row-split by h:
// each WG of the 4-WG group owns a 128-row h-slice of the S4 states for ALL
// 4 group batches (param regs drop 96->32; state regs unchanged), computes
// g locally (g-broadcast eliminated), computes partial z over its rows for
// all 512 outputs x 4 batches, then ONE all-gather of partials per block.
// Every WG redundantly sums partials (fixed mem order -> bitwise identical),
// and redundantly does LN/heads/decisions/ctx for all 4 batches, so decode
// decisions never need exchanging. Also: blk loop fully unrolled (rule #20:
// no runtime-selected state pointers -> no scratch), fold-exchange n-reduce
// (15 shfl, distributes y so every lane does 1 gelu instead of 16 on 1/16
// lanes), __launch_bounds__(512,1) (grid==CU count -> 1 WG/CU regardless;
// frees the 128-VGPR cap). Mailbox protocol (XCD handshake, plain-store +
// syncthreads-vmcnt-drain + sc0 loads fast path, agent-atomic slow path)
// kept verbatim from R7.

typedef float f32x4 __attribute__((ext_vector_type(4)));

__device__ __forceinline__ float gelu_f32(float x) {
    return 0.5f * x * (1.0f + erff(x * 0.70710678118654752440f));
}

__device__ __forceinline__ float sig32(float x) {
    return 1.0f / (1.0f + expf(-x));
}

// L2-coherent gather: issue 4 loads, single wait. sc0 bypasses (possibly
// stale) per-CU L1 and reads the XCD-shared L2 where producers' stores landed.
__device__ __forceinline__ void load4x4_l2(const f32x4* p0, const f32x4* p1,
                                           const f32x4* p2, const f32x4* p3,
                                           f32x4& v0, f32x4& v1, f32x4& v2, f32x4& v3) {
    asm volatile(
        "global_load_dwordx4 %0, %4, off sc0\n\t"
        "global_load_dwordx4 %1, %5, off sc0\n\t"
        "global_load_dwordx4 %2, %6, off sc0\n\t"
        "global_load_dwordx4 %3, %7, off sc0\n\t"
        "s_waitcnt vmcnt(0)"
        : "=&v"(v0), "=&v"(v1), "=&v"(v2), "=&v"(v3)
        : "v"(p0), "v"(p1), "v"(p2), "v"(p3)
        : "memory");
}

__device__ __forceinline__ void fma_row4(float4& acc, const float4 g,
                                         const float4 w0, const float4 w1,
                                         const float4 w2, const float4 w3) {
    acc.x = fmaf(g.w, w3.x, fmaf(g.z, w2.x, fmaf(g.y, w1.x, fmaf(g.x, w0.x, acc.x))));
    acc.y = fmaf(g.w, w3.y, fmaf(g.z, w2.y, fmaf(g.y, w1.y, fmaf(g.x, w0.y, acc.y))));
    acc.z = fmaf(g.w, w3.z, fmaf(g.z, w2.z, fmaf(g.y, w1.z, fmaf(g.x, w0.z, acc.z))));
    acc.w = fmaf(g.w, w3.w, fmaf(g.z, w2.w, fmaf(g.y, w1.w, fmaf(g.x, w0.w, acc.w))));
}

__global__ __launch_bounds__(NTHR, 1)
void s4_decode_kernel(
    const float* __restrict__ input_seq,   // (B,S,3)
    const float* __restrict__ in_W,        // (3,H)
    const float* __restrict__ in_b,        // (H)
    const float* __restrict__ Aarr,        // (L,H,N)
    const float* __restrict__ Barr,        // (L,H,N)
    const float* __restrict__ Carr,        // (L,H,N)
    const float* __restrict__ Darr,        // (L,H)
    const float* __restrict__ outW,        // (L,H,H)
    const float* __restrict__ outb,        // (L,H)
    const float* __restrict__ ln_g,        // (L,H)
    const float* __restrict__ ln_b,        // (L,H)
    const float* __restrict__ headW,       // (H,9)
    const float* __restrict__ headb,       // (9)
    float* __restrict__ out,               // (B,T,9)
    float* zws,                            // partial mailbox: 64 groups x 8192 f
    unsigned* fz,                          // flags (256), zeroed per launch
    unsigned* fx, unsigned* xid)           // XCD handshake, zeroed per launch
{
    __shared__ __align__(16) float  ld_x[4 * HDIM];     // block input (dp or xd0), 4 batches
    __shared__ __align__(16) float  ld_g[4 * GSTR];     // gelu out, own h-slice, 4 batches
    __shared__ float4 ld_z4[16 * 128];                  // 32 KB matvec partials
    __shared__ float  ld_red[64];                       // LN partials (8 waves x 8)
    __shared__ __align__(16) float  ld_hred[8 * 36];    // head partials
    __shared__ float  ld_logit[36];
    __shared__ float  ld_dec[16];                       // 4 batches x {c0,c1,c2,pad}
    __shared__ int    ld_ptr[4];
    __shared__ int    ld_fast;

    const int b     = blockIdx.x;
    const int tid   = threadIdx.x;
    const int n     = tid & 15;                 // state n-index
    const int hl32  = tid >> 4;                 // [0,32) h sub-position
    const int mem   = (b >> 3) & 3;             // slot in 4-WG group
    const int gbase = b - 8 * mem;              // group batches: gbase + 8j (same XCD mod-8)
    const int hbase = 128 * mem;                // own h-slice base
    const size_t zbase = (size_t)(((b >> 5) << 3) + (b & 7)) * (4 * HDIM * 4);

    // ---- XCD-id handshake: L2 fast path only if all 4 members co-XCD ----
    unsigned myxcd;
    asm volatile("s_getreg_b32 %0, hwreg(HW_REG_XCC_ID)" : "=s"(myxcd));
    if (tid == 0) {
        __hip_atomic_store(&xid[b], myxcd, __ATOMIC_RELAXED, __HIP_MEMORY_SCOPE_AGENT);
        __hip_atomic_store(&fx[b], 1u, __ATOMIC_RELEASE, __HIP_MEMORY_SCOPE_AGENT);
        unsigned ok = 1;
        #pragma unroll
        for (int j = 0; j < 4; ++j) {
            if (j == mem) continue;
            int guard = 0;
            while (__hip_atomic_load(&fx[gbase + 8 * j],
                                     __ATOMIC_ACQUIRE, __HIP_MEMORY_SCOPE_AGENT) == 0) {
                __builtin_amdgcn_s_sleep(1);
                if (++guard > SPIN_CAP) { ok = 0; break; }   // partner absent: degrade, don't hang
            }
            ok &= (__hip_atomic_load(&xid[gbase + 8 * j],
                                     __ATOMIC_RELAXED, __HIP_MEMORY_SCOPE_AGENT) == myxcd);
        }
        ld_fast = (int)ok;
    }

    // ---- persistent: states for own h-slice x ALL 4 batches; batch-shared params
    float s0[16], s1[16];                       // s[j*4+k]
    float A0[4], B0[4], C0[4], A1[4], B1[4], C1[4], Dm0[4], Dm1[4];
    #pragma unroll
    for (int k = 0; k < 4; ++k) {
        const int h  = hbase + hl32 + 32 * k;
        const int i0 = h * NDIM + n;
        const int i1 = (HDIM + h) * NDIM + n;
        A0[k] = Aarr[i0]; B0[k] = Barr[i0]; C0[k] = Carr[i0];
        A1[k] = Aarr[i1]; B1[k] = Barr[i1]; C1[k] = Carr[i1];
        // D*x folded into the n-reduction: only lane n==0 contributes it once
        Dm0[k] = (n == 0) ? Darr[h] : 0.f;
        Dm1[k] = (n == 0) ? Darr[HDIM + h] : 0.f;
    }
    #pragma unroll
    for (int v = 0; v < 16; ++v) { s0[v] = 0.f; s1[v] = 0.f; }

    const float inb_t = in_b[tid];
    const float w0 = in_W[tid], w1 = in_W[HDIM + tid], w2 = in_W[2 * HDIM + tid];
    const float ob0 = outb[tid], ob1 = outb[HDIM + tid];
    const float lg0 = ln_g[tid], lg1 = ln_g[HDIM + tid];
    const float lb0 = ln_b[tid], lb1 = ln_b[HDIM + tid];
    float hw[ODIM];
    #pragma unroll
    for (int o = 0; o < ODIM; ++o) hw[o] = headW[tid * ODIM + o];

    float ctx[4] = {0.f, 0.f, 0.f, 0.f};
    if (tid < 4) { ld_dec[4 * tid] = 0.f; ld_dec[4 * tid + 1] = 0.f; ld_dec[4 * tid + 2] = 1.f; }
    __syncthreads();
    const bool fast = (ld_fast != 0);           // wave-uniform

    for (int i = 0; i < TSTEPS; ++i) {
        // ---- decoder input projection, all 4 batches, at own column t ----
        float dpr[4];
        #pragma unroll
        for (int j = 0; j < 4; ++j) {
            dpr[j] = fmaf(ld_dec[4 * j], w0,
                     fmaf(ld_dec[4 * j + 1], w1,
                     fmaf(ld_dec[4 * j + 2], w2, inb_t)));
            ld_x[j * HDIM + tid] = dpr[j];
        }
        __syncthreads();

        float xn[4];

        #pragma unroll
        for (int blk = 0; blk < 2; ++blk) {
            const unsigned seq = (unsigned)(2 * i + blk + 1);

            // ---- S4 state update (own h-slice, 4 batches) + C*s (+D*x on n==0)
            float p[16];
            {
                float*       sp = blk ? s1 : s0;
                const float* Ar = blk ? A1 : A0;
                const float* Br = blk ? B1 : B0;
                const float* Cr = blk ? C1 : C0;
                const float* Dm = blk ? Dm1 : Dm0;
                #pragma unroll
                for (int j = 0; j < 4; ++j)
                    #pragma unroll
                    for (int k = 0; k < 4; ++k) {
                        const int v = j * 4 + k;
                        const float x  = ld_x[j * HDIM + hbase + hl32 + 32 * k];
                        const float sv = fmaf(Ar[k], sp[v], Br[k] * x);
                        sp[v] = sv;
                        p[v] = fmaf(Dm[k], x, sv * Cr[k]);
                    }
            }
            // ---- fold-exchange reduce over n (16 lanes, 16 values):
            //      lane n ends holding full sum of value v == n -> 1 gelu/lane
            {
                float q8[8];
                { const bool bt = (n & 1) != 0;
                  #pragma unroll
                  for (int u = 0; u < 8; ++u) {
                      const float sd = bt ? p[2 * u] : p[2 * u + 1];
                      const float rc = __shfl_xor(sd, 1);
                      q8[u] = (bt ? p[2 * u + 1] : p[2 * u]) + rc;
                  } }
                float q4[4];
                { const bool bt = (n & 2) != 0;
                  #pragma unroll
                  for (int u = 0; u < 4; ++u) {
                      const float sd = bt ? q8[2 * u] : q8[2 * u + 1];
                      const float rc = __shfl_xor(sd, 2);
                      q4[u] = (bt ? q8[2 * u + 1] : q8[2 * u]) + rc;
                  } }
                float q2[2];
                { const bool bt = (n & 4) != 0;
                  #pragma unroll
                  for (int u = 0; u < 2; ++u) {
                      const float sd = bt ? q4[2 * u] : q4[2 * u + 1];
                      const float rc = __shfl_xor(sd, 4);
                      q2[u] = (bt ? q4[2 * u + 1] : q4[2 * u]) + rc;
                  } }
                float y;
                { const bool bt = (n & 8) != 0;
                  const float sd = bt ? q2[0] : q2[1];
                  const float rc = __shfl_xor(sd, 8);
                  y = (bt ? q2[1] : q2[0]) + rc; }
                // lane n holds y for (batch j = n>>2, k = n&3) at this hl32
                ld_g[(n >> 2) * GSTR + hl32 + 32 * (n & 3)] = gelu_f32(y);
            }
            __syncthreads();

            // ---- matvec: own 128 rows x all 512 outputs x 4 batches ----
            {
                const int rg   = tid >> 7;             // row quarter [0,4)
                const int c    = tid & 127;            // float4 output column
                const int rge  = (rg + b) & 3;         // per-WG quarter rotation
                const int rb32 = rge * 32;
                const int roff = (b & 7) * 4;          // 4-aligned window rotation
                const float4* Wb = (const float4*)outW
                    + (((size_t)blk) << 16) + (size_t)(hbase + rb32) * 128 + c;
                float4 acc0 = make_float4(0.f, 0.f, 0.f, 0.f);
                float4 acc1 = acc0, acc2 = acc0, acc3 = acc0;
                int r = roff;
                float4 cw0 = Wb[(size_t)(r + 0) * 128], cw1 = Wb[(size_t)(r + 1) * 128],
                       cw2 = Wb[(size_t)(r + 2) * 128], cw3 = Wb[(size_t)(r + 3) * 128];
                #pragma unroll
                for (int ch = 0; ch < 8; ++ch) {
                    float4 nw0, nw1, nw2, nw3;
                    const int rn = (roff + 4 * ch + 4) & 31;
                    if (ch < 7) {
                        nw0 = Wb[(size_t)(rn + 0) * 128]; nw1 = Wb[(size_t)(rn + 1) * 128];
                        nw2 = Wb[(size_t)(rn + 2) * 128]; nw3 = Wb[(size_t)(rn + 3) * 128];
                    }
                    const float4 g0 = *(const float4*)&ld_g[0 * GSTR + rb32 + r];
                    const float4 g1 = *(const float4*)&ld_g[1 * GSTR + rb32 + r];
                    const float4 g2 = *(const float4*)&ld_g[2 * GSTR + rb32 + r];
                    const float4 g3 = *(const float4*)&ld_g[3 * GSTR + rb32 + r];
                    fma_row4(acc0, g0, cw0, cw1, cw2, cw3);
                    fma_row4(acc1, g1, cw0, cw1, cw2, cw3);
                    fma_row4(acc2, g2, cw0, cw1, cw2, cw3);
                    fma_row4(acc3, g3, cw0, cw1, cw2, cw3);
                    if (ch < 7) { cw0 = nw0; cw1 = nw1; cw2 = nw2; cw3 = nw3; r = rn; }
                }
                ld_z4[(rg * 4 + 0) * 128 + c] = acc0;
                ld_z4[(rg * 4 + 1) * 128 + c] = acc1;
                ld_z4[(rg * 4 + 2) * 128 + c] = acc2;
                ld_z4[(rg * 4 + 3) * 128 + c] = acc3;
            }
            __syncthreads();

            // ---- combine row quarters, publish partials [b][o][mem] ----
            {
                const int b2 = tid >> 7;
                const int c  = tid & 127;
                const float4 z0 = ld_z4[(0 * 4 + b2) * 128 + c];
                const float4 z1 = ld_z4[(1 * 4 + b2) * 128 + c];
                const float4 z2 = ld_z4[(2 * 4 + b2) * 128 + c];
                const float4 z3 = ld_z4[(3 * 4 + b2) * 128 + c];
                const float sx = ((z0.x + z1.x) + z2.x) + z3.x;
                const float sy = ((z0.y + z1.y) + z2.y) + z3.y;
                const float sz = ((z0.z + z1.z) + z2.z) + z3.z;
                const float sw = ((z0.w + z1.w) + z2.w) + z3.w;
                float* zp = zws + zbase + (size_t)(b2 * HDIM + 4 * c) * 4 + mem;
                if (fast) {
                    zp[0] = sx; zp[4] = sy; zp[8] = sz; zp[12] = sw;
                } else {
                    __hip_atomic_store(zp + 0,  sx, __ATOMIC_RELAXED, __HIP_MEMORY_SCOPE_AGENT);
                    __hip_atomic_store(zp + 4,  sy, __ATOMIC_RELAXED, __HIP_MEMORY_SCOPE_AGENT);
                    __hip_atomic_store(zp + 8,  sz, __ATOMIC_RELAXED, __HIP_MEMORY_SCOPE_AGENT);
                    __hip_atomic_store(zp + 12, sw, __ATOMIC_RELAXED, __HIP_MEMORY_SCOPE_AGENT);
                }
            }
            __syncthreads();                    // drains vmcnt -> partials in L2
            if (tid == 4)
                __hip_atomic_store(&fz[b], seq, __ATOMIC_RELAXED, __HIP_MEMORY_SCOPE_AGENT);
            if (tid < 3) {                      // parallel polling, one flag each
                const int j = tid + (tid >= mem ? 1 : 0);
                int guard = 0;
                while (__hip_atomic_load(&fz[gbase + 8 * j],
                                         __ATOMIC_RELAXED, __HIP_MEMORY_SCOPE_AGENT) < seq) {
                    __builtin_amdgcn_s_sleep(1);
                    if (++guard > SPIN_CAP) break;   // deadlock -> wrong-answer diagnostic
                }
            }
            __syncthreads();

            // ---- gather 4 partials x 4 batches at o = tid; fixed mem order ----
            float z[4];
            {
                const float ob = blk ? ob1 : ob0;
                if (fast) {
                    const f32x4* zq = (const f32x4*)(zws + zbase);
                    f32x4 m0, m1, m2, m3;
                    load4x4_l2(zq + 0 * HDIM + tid, zq + 1 * HDIM + tid,
                               zq + 2 * HDIM + tid, zq + 3 * HDIM + tid, m0, m1, m2, m3);
                    z[0] = (((m0.x + m0.y) + m0.z) + m0.w) + ob;
                    z[1] = (((m1.x + m1.y) + m1.z) + m1.w) + ob;
                    z[2] = (((m2.x + m2.y) + m2.z) + m2.w) + ob;
                    z[3] = (((m3.x + m3.y) + m3.z) + m3.w) + ob;
                } else {
                    #pragma unroll
                    for (int j = 0; j < 4; ++j) {
                        const float* zf = zws + zbase + (size_t)(j * HDIM + tid) * 4;
                        const float a0 = __hip_atomic_load(zf + 0, __ATOMIC_RELAXED, __HIP_MEMORY_SCOPE_AGENT);
                        const float a1 = __hip_atomic_load(zf + 1, __ATOMIC_RELAXED, __HIP_MEMORY_SCOPE_AGENT);
                        const float a2 = __hip_atomic_load(zf + 2, __ATOMIC_RELAXED, __HIP_MEMORY_SCOPE_AGENT);
                        const float a3 = __hip_atomic_load(zf + 3, __ATOMIC_RELAXED, __HIP_MEMORY_SCOPE_AGENT);
                        z[j] = (((a0 + a1) + a2) + a3) + ob;
                    }
                }
            }

            // ---- residual + one-pass LN, all 4 batches (replicated) ----
            {
                float tmp[4], v1[4], v2[4];
                #pragma unroll
                for (int j = 0; j < 4; ++j) {
                    const float res = (i == 0) ? dpr[j] : z[j];   // ref: res=proj @ i==0
                    tmp[j] = z[j] + res;
                    v1[j] = tmp[j];
                    v2[j] = tmp[j] * tmp[j];
                }
                #pragma unroll
                for (int m = 1; m < 64; m <<= 1) {
                    #pragma unroll
                    for (int j = 0; j < 4; ++j) {
                        v1[j] += __shfl_xor(v1[j], m);
                        v2[j] += __shfl_xor(v2[j], m);
                    }
                }
                if ((tid & 63) == 0) {
                    const int wv = tid >> 6;
                    #pragma unroll
                    for (int j = 0; j < 4; ++j) {
                        ld_red[wv * 8 + 2 * j]     = v1[j];
                        ld_red[wv * 8 + 2 * j + 1] = v2[j];
                    }
                }
                __syncthreads();
                const float glG = blk ? lg1 : lg0;
                const float glB = blk ? lb1 : lb0;
                #pragma unroll
                for (int j = 0; j < 4; ++j) {
                    float s1r = 0.f, s2r = 0.f;
                    #pragma unroll
                    for (int q = 0; q < 8; ++q) {
                        s1r += ld_red[q * 8 + 2 * j];
                        s2r += ld_red[q * 8 + 2 * j + 1];
                    }
                    const float mu  = s1r * (1.f / 512.f);
                    const float var = s2r * (1.f / 512.f) - mu * mu;
                    const float rs  = rsqrtf(var + 1e-5f);
                    xn[j] = (tmp[j] - mu) * rs * glG + glB;
                }
                if (blk == 0) {
                    #pragma unroll
                    for (int j = 0; j < 4; ++j) ld_x[j * HDIM + tid] = xn[j];
                    __syncthreads();
                }
            }
        } // blk

        // ================= head #1 (all 4 batches, replicated) =================
        {
            float hp[36];
            #pragma unroll
            for (int j = 0; j < 4; ++j) {
                const float v = xn[j] + ctx[j];
                #pragma unroll
                for (int o = 0; o < ODIM; ++o) hp[j * ODIM + o] = v * hw[o];
            }
            #pragma unroll
            for (int m = 1; m < 64; m <<= 1)
                #pragma unroll
                for (int u = 0; u < 36; ++u) hp[u] += __shfl_xor(hp[u], m);
            if ((tid & 63) == 0) {
                float4* hd = (float4*)&ld_hred[(tid >> 6) * 36];
                #pragma unroll
                for (int u = 0; u < 9; ++u)
                    hd[u] = make_float4(hp[4 * u], hp[4 * u + 1], hp[4 * u + 2], hp[4 * u + 3]);
            }
            __syncthreads();
            if (tid < 36) {
                float s = headb[tid % ODIM];
                #pragma unroll
                for (int q = 0; q < 8; ++q) s += ld_hred[q * 36 + tid];
                ld_logit[tid] = s;
            }
            __syncthreads();
        }

        const bool is_out = ((i & 1) == 0);
        if (is_out) {
            if (tid < ODIM)
                out[((size_t)b * TSTEPS + i) * ODIM + tid] = sig32(ld_logit[mem * ODIM + tid]);
            if (tid < 4) {
                const float nc = (sig32(ld_logit[tid * ODIM]) > 0.5f) ? 1.f : 0.f;
                ld_dec[4 * tid] = nc; ld_dec[4 * tid + 1] = 1.f; ld_dec[4 * tid + 2] = 0.f;
            }
            __syncthreads();
        } else {
            // np.argmax over f32 SIGMOIDS (saturation => not logit-argmax!)
            if (tid < 4) {
                const int base9 = tid * ODIM;
                int best = 0; float bv = sig32(ld_logit[base9 + 3]);
                #pragma unroll
                for (int o = 1; o < 6; ++o) {
                    const float v2 = sig32(ld_logit[base9 + 3 + o]);
                    if (v2 > bv) { bv = v2; best = o; }
                }
                ld_ptr[tid] = best;
                ld_dec[4 * tid] = 0.f; ld_dec[4 * tid + 1] = 0.f; ld_dec[4 * tid + 2] = 1.f;
            }
            __syncthreads();
            // ctx[j] += encoded[batch_j, ptr_j, :] at own column t
            #pragma unroll
            for (int j = 0; j < 4; ++j) {
                const float* iseq = input_seq + ((size_t)(gbase + 8 * j) * SEQ + ld_ptr[j]) * 3;
                ctx[j] += fmaf(iseq[0], w0, fmaf(iseq[1], w1, fmaf(iseq[2], w2, inb_t)));
            }
            // ================= head #2 (post-ctx-update) =================
            {
                float hq[36];
                #pragma unroll
                for (int j = 0; j < 4; ++j) {
                    const float v = xn[j] + ctx[j];
                    #pragma unroll
                    for (int o = 0; o < ODIM; ++o) hq[j * ODIM + o] = v * hw[o];
                }
                #pragma unroll
                for (int m = 1; m < 64; m <<= 1)
                    #pragma unroll
                    for (int u = 0; u < 36; ++u) hq[u] += __shfl_xor(hq[u], m);
                if ((tid & 63) == 0) {
                    float4* hd = (float4*)&ld_hred[(tid >> 6) * 36];
                    #pragma unroll
                    for (int u = 0; u < 9; ++u)
                        hd[u] = make_float4(hq[4 * u], hq[4 * u + 1], hq[4 * u + 2], hq[4 * u + 3]);
                }
                __syncthreads();
                if (tid < ODIM) {
                    float s = headb[tid];
                    #pragma unroll
                    for (int q = 0; q < 8; ++q) s += ld_hred[q * 36 + mem * ODIM + tid];
                    out[((size_t)b * TSTEPS + i) * ODIM + tid] = sig32(s);
                }
                __syncthreads();
            }
        }
    }
}

extern "C" void kernel_launch(void* const* d_in, const int* in_sizes, int n_in,
                              void* d_out, int out_size, void* d_ws, size_t ws_size,
                              hipStream_t stream) {
    (void)in_sizes; (void)n_in; (void)ws_size; (void)out_size;
    const float* input_seq = (const float*)d_in[0];
    // d_in[1] = autoregressive_steps (scalar) -- T fixed at 63 by the model
    const float* in_W   = (const float*)d_in[2];
    const float* in_b   = (const float*)d_in[3];
    const float* Aarr   = (const float*)d_in[4];
    const float* Barr   = (const float*)d_in[5];
    const float* Carr   = (const float*)d_in[6];
    const float* Darr   = (const float*)d_in[7];
    const float* outW   = (const float*)d_in[8];
    const float* outb   = (const float*)d_in[9];
    const float* ln_g   = (const float*)d_in[10];
    const float* ln_b   = (const float*)d_in[11];
    const float* headW  = (const float*)d_in[12];
    const float* headb  = (const float*)d_in[13];
    float* out = (float*)d_out;

    // ws layout: fg [0,1K) (legacy, unused), fz [1K,2K), fx [2K,3K), xid [3K,4K),
    // zws [4K, 4K+2MB): 64 groups x (4 batches x 512 o x 4 mem) partials
    unsigned* fz  = (unsigned*)d_ws + BATCH;
    unsigned* fx  = (unsigned*)d_ws + 2 * BATCH;
    unsigned* xid = (unsigned*)d_ws + 3 * BATCH;
    float* zws = (float*)((char*)d_ws + 4096);

    // zero all flags every launch (ws is poisoned 0xAA by the harness)
    hipMemsetAsync(d_ws, 0, 4096, stream);

    s4_decode_kernel<<<BATCH, NTHR, 0, stream>>>(
        input_seq, in_W, in_b, Aarr, Barr, Carr, Darr,
        outW, outb, ln_g, ln_b, headW, headb, out,
        zws, fz, fx, xid);
}

// Round 3
// 2840.152 us; speedup vs baseline: 1.0230x; 1.0230x over previous
//
#include <hip/hip_runtime.h>
#include <math.h>

// Problem constants (fixed by the reference)
#define HDIM   512
#define NDIM   16
#define SEQ    64
#define TSTEPS 63
#define BATCH  256
#define ODIM   9
#define NTHR   512
#define GSTR   132   // bank-padded row stride for ld_g
#define SPIN_CAP (1 << 24)   // ~0.45s of s_sleep(1): converts deadlock -> wrong-answer diag

// R10 = R9 structure with the mailbox un-interleaved (R9 post-mortem):
// R9's 4B-interleaved-by-mem mailbox lines were co-written by 4 CUs in
// partial sectors -> L2 merge/RMW round-trips -> FETCH 4.15GB, WRITE 1.55GB,
// 2x slowdown. R10 layout zws[group][mem][batch][512]: every line written
// contiguously by exactly ONE producer WG (R7's proven discipline).
// Gather is cooperative: thread (b2,c) sums 4 mem-partials (4x dwordx4 sc0,
// single wait, fixed m order -> bitwise identical everywhere), redistributes
// via an 8KB LDS buffer. One rendezvous per S4 block (2/step) retained:
// row-split by h (each WG owns 128 h-rows of S4 state for all 4 group
// batches), g computed locally, matvec partial over own rows for all 512
// outputs x 4 batches, replicated LN/heads/decisions (no decision exchange).
// Bounded spins kept. Fast/slow path by XCD handshake kept.

typedef float f32x4 __attribute__((ext_vector_type(4)));

__device__ __forceinline__ float gelu_f32(float x) {
    return 0.5f * x * (1.0f + erff(x * 0.70710678118654752440f));
}

__device__ __forceinline__ float sig32(float x) {
    return 1.0f / (1.0f + expf(-x));
}

// L2-coherent gather: issue 4 loads, single wait. sc0 bypasses (possibly
// stale) per-CU L1 and reads the XCD-shared L2 where producers' stores landed.
__device__ __forceinline__ void load4x4_l2(const f32x4* p0, const f32x4* p1,
                                           const f32x4* p2, const f32x4* p3,
                                           f32x4& v0, f32x4& v1, f32x4& v2, f32x4& v3) {
    asm volatile(
        "global_load_dwordx4 %0, %4, off sc0\n\t"
        "global_load_dwordx4 %1, %5, off sc0\n\t"
        "global_load_dwordx4 %2, %6, off sc0\n\t"
        "global_load_dwordx4 %3, %7, off sc0\n\t"
        "s_waitcnt vmcnt(0)"
        : "=&v"(v0), "=&v"(v1), "=&v"(v2), "=&v"(v3)
        : "v"(p0), "v"(p1), "v"(p2), "v"(p3)
        : "memory");
}

__device__ __forceinline__ void fma_row4(float4& acc, const float4 g,
                                         const float4 w0, const float4 w1,
                                         const float4 w2, const float4 w3) {
    acc.x = fmaf(g.w, w3.x, fmaf(g.z, w2.x, fmaf(g.y, w1.x, fmaf(g.x, w0.x, acc.x))));
    acc.y = fmaf(g.w, w3.y, fmaf(g.z, w2.y, fmaf(g.y, w1.y, fmaf(g.x, w0.y, acc.y))));
    acc.z = fmaf(g.w, w3.z, fmaf(g.z, w2.z, fmaf(g.y, w1.z, fmaf(g.x, w0.z, acc.z))));
    acc.w = fmaf(g.w, w3.w, fmaf(g.z, w2.w, fmaf(g.y, w1.w, fmaf(g.x, w0.w, acc.w))));
}

__global__ __launch_bounds__(NTHR, 1)
void s4_decode_kernel(
    const float* __restrict__ input_seq,   // (B,S,3)
    const float* __restrict__ in_W,        // (3,H)
    const float* __restrict__ in_b,        // (H)
    const float* __restrict__ Aarr,        // (L,H,N)
    const float* __restrict__ Barr,        // (L,H,N)
    const float* __restrict__ Carr,        // (L,H,N)
    const float* __restrict__ Darr,        // (L,H)
    const float* __restrict__ outW,        // (L,H,H)
    const float* __restrict__ outb,        // (L,H)
    const float* __restrict__ ln_g,        // (L,H)
    const float* __restrict__ ln_b,        // (L,H)
    const float* __restrict__ headW,       // (H,9)
    const float* __restrict__ headb,       // (9)
    float* __restrict__ out,               // (B,T,9)
    float* zws,                            // partial mailbox: 64 groups x 8192 f
    unsigned* fz,                          // flags (256), zeroed per launch
    unsigned* fx, unsigned* xid)           // XCD handshake, zeroed per launch
{
    __shared__ __align__(16) float  ld_x[4 * HDIM];     // block input (dp or xd0), 4 batches
    __shared__ __align__(16) float  ld_g[4 * GSTR];     // gelu out, own h-slice, 4 batches
    __shared__ float4 ld_z4[16 * 128];                  // 32 KB matvec partials
    __shared__ __align__(16) float  ld_zred[4 * HDIM];  // 8 KB gathered z, 4 batches
    __shared__ float  ld_red[64];                       // LN partials (8 waves x 8)
    __shared__ __align__(16) float  ld_hred[8 * 36];    // head partials
    __shared__ float  ld_logit[36];
    __shared__ float  ld_dec[16];                       // 4 batches x {c0,c1,c2,pad}
    __shared__ int    ld_ptr[4];
    __shared__ int    ld_fast;

    const int b     = blockIdx.x;
    const int tid   = threadIdx.x;
    const int n     = tid & 15;                 // state n-index
    const int hl32  = tid >> 4;                 // [0,32) h sub-position
    const int mem   = (b >> 3) & 3;             // slot in 4-WG group
    const int gbase = b - 8 * mem;              // group batches: gbase + 8j (same XCD mod-8)
    const int hbase = 128 * mem;                // own h-slice base
    const size_t zbase = (size_t)(((b >> 5) << 3) + (b & 7)) * (4 * 4 * HDIM);

    // ---- XCD-id handshake: L2 fast path only if all 4 members co-XCD ----
    unsigned myxcd;
    asm volatile("s_getreg_b32 %0, hwreg(HW_REG_XCC_ID)" : "=s"(myxcd));
    if (tid == 0) {
        __hip_atomic_store(&xid[b], myxcd, __ATOMIC_RELAXED, __HIP_MEMORY_SCOPE_AGENT);
        __hip_atomic_store(&fx[b], 1u, __ATOMIC_RELEASE, __HIP_MEMORY_SCOPE_AGENT);
        unsigned ok = 1;
        #pragma unroll
        for (int j = 0; j < 4; ++j) {
            if (j == mem) continue;
            int guard = 0;
            while (__hip_atomic_load(&fx[gbase + 8 * j],
                                     __ATOMIC_ACQUIRE, __HIP_MEMORY_SCOPE_AGENT) == 0) {
                __builtin_amdgcn_s_sleep(1);
                if (++guard > SPIN_CAP) { ok = 0; break; }   // partner absent: degrade, don't hang
            }
            ok &= (__hip_atomic_load(&xid[gbase + 8 * j],
                                     __ATOMIC_RELAXED, __HIP_MEMORY_SCOPE_AGENT) == myxcd);
        }
        ld_fast = (int)ok;
    }

    // ---- persistent: states for own h-slice x ALL 4 batches; batch-shared params
    float s0[16], s1[16];                       // s[j*4+k]
    float A0[4], B0[4], C0[4], A1[4], B1[4], C1[4], Dm0[4], Dm1[4];
    #pragma unroll
    for (int k = 0; k < 4; ++k) {
        const int h  = hbase + hl32 + 32 * k;
        const int i0 = h * NDIM + n;
        const int i1 = (HDIM + h) * NDIM + n;
        A0[k] = Aarr[i0]; B0[k] = Barr[i0]; C0[k] = Carr[i0];
        A1[k] = Aarr[i1]; B1[k] = Barr[i1]; C1[k] = Carr[i1];
        // D*x folded into the n-reduction: only lane n==0 contributes it once
        Dm0[k] = (n == 0) ? Darr[h] : 0.f;
        Dm1[k] = (n == 0) ? Darr[HDIM + h] : 0.f;
    }
    #pragma unroll
    for (int v = 0; v < 16; ++v) { s0[v] = 0.f; s1[v] = 0.f; }

    const float inb_t = in_b[tid];
    const float w0 = in_W[tid], w1 = in_W[HDIM + tid], w2 = in_W[2 * HDIM + tid];
    const float ob0 = outb[tid], ob1 = outb[HDIM + tid];
    const float lg0 = ln_g[tid], lg1 = ln_g[HDIM + tid];
    const float lb0 = ln_b[tid], lb1 = ln_b[HDIM + tid];
    float hw[ODIM];
    #pragma unroll
    for (int o = 0; o < ODIM; ++o) hw[o] = headW[tid * ODIM + o];

    float ctx[4] = {0.f, 0.f, 0.f, 0.f};
    if (tid < 4) { ld_dec[4 * tid] = 0.f; ld_dec[4 * tid + 1] = 0.f; ld_dec[4 * tid + 2] = 1.f; }
    __syncthreads();
    const bool fast = (ld_fast != 0);           // wave-uniform

    for (int i = 0; i < TSTEPS; ++i) {
        // ---- decoder input projection, all 4 batches, at own column t ----
        float dpr[4];
        #pragma unroll
        for (int j = 0; j < 4; ++j) {
            dpr[j] = fmaf(ld_dec[4 * j], w0,
                     fmaf(ld_dec[4 * j + 1], w1,
                     fmaf(ld_dec[4 * j + 2], w2, inb_t)));
            ld_x[j * HDIM + tid] = dpr[j];
        }
        __syncthreads();

        float xn[4];

        #pragma unroll
        for (int blk = 0; blk < 2; ++blk) {
            const unsigned seq = (unsigned)(2 * i + blk + 1);

            // ---- S4 state update (own h-slice, 4 batches) + C*s (+D*x on n==0)
            float p[16];
            {
                float*       sp = blk ? s1 : s0;
                const float* Ar = blk ? A1 : A0;
                const float* Br = blk ? B1 : B0;
                const float* Cr = blk ? C1 : C0;
                const float* Dm = blk ? Dm1 : Dm0;
                #pragma unroll
                for (int j = 0; j < 4; ++j)
                    #pragma unroll
                    for (int k = 0; k < 4; ++k) {
                        const int v = j * 4 + k;
                        const float x  = ld_x[j * HDIM + hbase + hl32 + 32 * k];
                        const float sv = fmaf(Ar[k], sp[v], Br[k] * x);
                        sp[v] = sv;
                        p[v] = fmaf(Dm[k], x, sv * Cr[k]);
                    }
            }
            // ---- fold-exchange reduce over n (16 lanes, 16 values):
            //      lane n ends holding full sum of value v == n -> 1 gelu/lane
            {
                float q8[8];
                { const bool bt = (n & 1) != 0;
                  #pragma unroll
                  for (int u = 0; u < 8; ++u) {
                      const float sd = bt ? p[2 * u] : p[2 * u + 1];
                      const float rc = __shfl_xor(sd, 1);
                      q8[u] = (bt ? p[2 * u + 1] : p[2 * u]) + rc;
                  } }
                float q4[4];
                { const bool bt = (n & 2) != 0;
                  #pragma unroll
                  for (int u = 0; u < 4; ++u) {
                      const float sd = bt ? q8[2 * u] : q8[2 * u + 1];
                      const float rc = __shfl_xor(sd, 2);
                      q4[u] = (bt ? q8[2 * u + 1] : q8[2 * u]) + rc;
                  } }
                float q2[2];
                { const bool bt = (n & 4) != 0;
                  #pragma unroll
                  for (int u = 0; u < 2; ++u) {
                      const float sd = bt ? q4[2 * u] : q4[2 * u + 1];
                      const float rc = __shfl_xor(sd, 4);
                      q2[u] = (bt ? q4[2 * u + 1] : q4[2 * u]) + rc;
                  } }
                float y;
                { const bool bt = (n & 8) != 0;
                  const float sd = bt ? q2[0] : q2[1];
                  const float rc = __shfl_xor(sd, 8);
                  y = (bt ? q2[1] : q2[0]) + rc; }
                // lane n holds y for (batch j = n>>2, k = n&3) at this hl32
                ld_g[(n >> 2) * GSTR + hl32 + 32 * (n & 3)] = gelu_f32(y);
            }
            __syncthreads();

            // ---- matvec: own 128 rows x all 512 outputs x 4 batches ----
            {
                const int rg   = tid >> 7;             // row quarter [0,4)
                const int c    = tid & 127;            // float4 output column
                const int rge  = (rg + b) & 3;         // per-WG quarter rotation
                const int rb32 = rge * 32;
                const int roff = (b & 7) * 4;          // 4-aligned window rotation
                const float4* Wb = (const float4*)outW
                    + (((size_t)blk) << 16) + (size_t)(hbase + rb32) * 128 + c;
                float4 acc0 = make_float4(0.f, 0.f, 0.f, 0.f);
                float4 acc1 = acc0, acc2 = acc0, acc3 = acc0;
                int r = roff;
                float4 cw0 = Wb[(size_t)(r + 0) * 128], cw1 = Wb[(size_t)(r + 1) * 128],
                       cw2 = Wb[(size_t)(r + 2) * 128], cw3 = Wb[(size_t)(r + 3) * 128];
                #pragma unroll
                for (int ch = 0; ch < 8; ++ch) {
                    float4 nw0, nw1, nw2, nw3;
                    const int rn = (roff + 4 * ch + 4) & 31;
                    if (ch < 7) {
                        nw0 = Wb[(size_t)(rn + 0) * 128]; nw1 = Wb[(size_t)(rn + 1) * 128];
                        nw2 = Wb[(size_t)(rn + 2) * 128]; nw3 = Wb[(size_t)(rn + 3) * 128];
                    }
                    const float4 g0 = *(const float4*)&ld_g[0 * GSTR + rb32 + r];
                    const float4 g1 = *(const float4*)&ld_g[1 * GSTR + rb32 + r];
                    const float4 g2 = *(const float4*)&ld_g[2 * GSTR + rb32 + r];
                    const float4 g3 = *(const float4*)&ld_g[3 * GSTR + rb32 + r];
                    fma_row4(acc0, g0, cw0, cw1, cw2, cw3);
                    fma_row4(acc1, g1, cw0, cw1, cw2, cw3);
                    fma_row4(acc2, g2, cw0, cw1, cw2, cw3);
                    fma_row4(acc3, g3, cw0, cw1, cw2, cw3);
                    if (ch < 7) { cw0 = nw0; cw1 = nw1; cw2 = nw2; cw3 = nw3; r = rn; }
                }
                ld_z4[(rg * 4 + 0) * 128 + c] = acc0;
                ld_z4[(rg * 4 + 1) * 128 + c] = acc1;
                ld_z4[(rg * 4 + 2) * 128 + c] = acc2;
                ld_z4[(rg * 4 + 3) * 128 + c] = acc3;
            }
            __syncthreads();

            // ---- combine row quarters, publish partial [mem][batch][512] ----
            // Producer-contiguous lines: this WG exclusively owns its 8KB slab.
            {
                const int b2 = tid >> 7;
                const int c  = tid & 127;
                const float4 z0 = ld_z4[(0 * 4 + b2) * 128 + c];
                const float4 z1 = ld_z4[(1 * 4 + b2) * 128 + c];
                const float4 z2 = ld_z4[(2 * 4 + b2) * 128 + c];
                const float4 z3 = ld_z4[(3 * 4 + b2) * 128 + c];
                const float sx = ((z0.x + z1.x) + z2.x) + z3.x;
                const float sy = ((z0.y + z1.y) + z2.y) + z3.y;
                const float sz = ((z0.z + z1.z) + z2.z) + z3.z;
                const float sw = ((z0.w + z1.w) + z2.w) + z3.w;
                float* zp = zws + zbase + (size_t)((mem * 4 + b2) * HDIM) + 4 * c;
                if (fast) {
                    *(float4*)zp = make_float4(sx, sy, sz, sw);
                } else {
                    __hip_atomic_store(zp + 0, sx, __ATOMIC_RELAXED, __HIP_MEMORY_SCOPE_AGENT);
                    __hip_atomic_store(zp + 1, sy, __ATOMIC_RELAXED, __HIP_MEMORY_SCOPE_AGENT);
                    __hip_atomic_store(zp + 2, sz, __ATOMIC_RELAXED, __HIP_MEMORY_SCOPE_AGENT);
                    __hip_atomic_store(zp + 3, sw, __ATOMIC_RELAXED, __HIP_MEMORY_SCOPE_AGENT);
                }
            }
            __syncthreads();                    // drains vmcnt -> partials in L2
            if (tid == 4)
                __hip_atomic_store(&fz[b], seq, __ATOMIC_RELAXED, __HIP_MEMORY_SCOPE_AGENT);
            if (tid < 3) {                      // parallel polling, one flag each
                const int j = tid + (tid >= mem ? 1 : 0);
                int guard = 0;
                while (__hip_atomic_load(&fz[gbase + 8 * j],
                                         __ATOMIC_RELAXED, __HIP_MEMORY_SCOPE_AGENT) < seq) {
                    __builtin_amdgcn_s_sleep(1);
                    if (++guard > SPIN_CAP) break;   // deadlock -> wrong-answer diagnostic
                }
            }
            __syncthreads();

            // ---- cooperative gather: thread (b2,c) sums 4 mem-partials for
            //      batch b2, cols 4c..4c+3 (fixed m order -> identical in all
            //      WGs), redistribute via LDS ----
            {
                const int b2 = tid >> 7;
                const int c  = tid & 127;
                f32x4 zs;
                if (fast) {
                    const f32x4* zq = (const f32x4*)(zws + zbase);
                    f32x4 m0, m1, m2, m3;
                    load4x4_l2(zq + (0 * 4 + b2) * 128 + c, zq + (1 * 4 + b2) * 128 + c,
                               zq + (2 * 4 + b2) * 128 + c, zq + (3 * 4 + b2) * 128 + c,
                               m0, m1, m2, m3);
                    zs = ((m0 + m1) + m2) + m3;
                } else {
                    #pragma unroll
                    for (int e = 0; e < 4; ++e) {
                        float acc = 0.f;
                        #pragma unroll
                        for (int m = 0; m < 4; ++m) {
                            const float* zf = zws + zbase
                                + (size_t)((m * 4 + b2) * HDIM) + 4 * c + e;
                            acc += __hip_atomic_load(zf, __ATOMIC_RELAXED,
                                                     __HIP_MEMORY_SCOPE_AGENT);
                        }
                        zs[e] = acc;
                    }
                }
                *(f32x4*)&ld_zred[b2 * HDIM + 4 * c] = zs;
            }
            __syncthreads();

            // ---- residual + one-pass LN, all 4 batches (replicated) ----
            {
                const float ob = blk ? ob1 : ob0;
                float z[4], tmp[4], v1[4], v2[4];
                #pragma unroll
                for (int j = 0; j < 4; ++j) {
                    z[j] = ld_zred[j * HDIM + tid] + ob;
                    const float res = (i == 0) ? dpr[j] : z[j];   // ref: res=proj @ i==0
                    tmp[j] = z[j] + res;
                    v1[j] = tmp[j];
                    v2[j] = tmp[j] * tmp[j];
                }
                #pragma unroll
                for (int m = 1; m < 64; m <<= 1) {
                    #pragma unroll
                    for (int j = 0; j < 4; ++j) {
                        v1[j] += __shfl_xor(v1[j], m);
                        v2[j] += __shfl_xor(v2[j], m);
                    }
                }
                if ((tid & 63) == 0) {
                    const int wv = tid >> 6;
                    #pragma unroll
                    for (int j = 0; j < 4; ++j) {
                        ld_red[wv * 8 + 2 * j]     = v1[j];
                        ld_red[wv * 8 + 2 * j + 1] = v2[j];
                    }
                }
                __syncthreads();
                const float glG = blk ? lg1 : lg0;
                const float glB = blk ? lb1 : lb0;
                #pragma unroll
                for (int j = 0; j < 4; ++j) {
                    float s1r = 0.f, s2r = 0.f;
                    #pragma unroll
                    for (int q = 0; q < 8; ++q) {
                        s1r += ld_red[q * 8 + 2 * j];
                        s2r += ld_red[q * 8 + 2 * j + 1];
                    }
                    const float mu  = s1r * (1.f / 512.f);
                    const float var = s2r * (1.f / 512.f) - mu * mu;
                    const float rs  = rsqrtf(var + 1e-5f);
                    xn[j] = (tmp[j] - mu) * rs * glG + glB;
                }
                if (blk == 0) {
                    __syncthreads();            // ld_red consumed; ld_x rewrite safe
                    #pragma unroll
                    for (int j = 0; j < 4; ++j) ld_x[j * HDIM + tid] = xn[j];
                    __syncthreads();
                }
            }
        } // blk

        // ================= head #1 (all 4 batches, replicated) =================
        {
            float hp[36];
            #pragma unroll
            for (int j = 0; j < 4; ++j) {
                const float v = xn[j] + ctx[j];
                #pragma unroll
                for (int o = 0; o < ODIM; ++o) hp[j * ODIM + o] = v * hw[o];
            }
            #pragma unroll
            for (int m = 1; m < 64; m <<= 1)
                #pragma unroll
                for (int u = 0; u < 36; ++u) hp[u] += __shfl_xor(hp[u], m);
            if ((tid & 63) == 0) {
                float4* hd = (float4*)&ld_hred[(tid >> 6) * 36];
                #pragma unroll
                for (int u = 0; u < 9; ++u)
                    hd[u] = make_float4(hp[4 * u], hp[4 * u + 1], hp[4 * u + 2], hp[4 * u + 3]);
            }
            __syncthreads();
            if (tid < 36) {
                float s = headb[tid % ODIM];
                #pragma unroll
                for (int q = 0; q < 8; ++q) s += ld_hred[q * 36 + tid];
                ld_logit[tid] = s;
            }
            __syncthreads();
        }

        const bool is_out = ((i & 1) == 0);
        if (is_out) {
            if (tid < ODIM)
                out[((size_t)b * TSTEPS + i) * ODIM + tid] = sig32(ld_logit[mem * ODIM + tid]);
            if (tid < 4) {
                const float nc = (sig32(ld_logit[tid * ODIM]) > 0.5f) ? 1.f : 0.f;
                ld_dec[4 * tid] = nc; ld_dec[4 * tid + 1] = 1.f; ld_dec[4 * tid + 2] = 0.f;
            }
            __syncthreads();
        } else {
            // np.argmax over f32 SIGMOIDS (saturation => not logit-argmax!)
            if (tid < 4) {
                const int base9 = tid * ODIM;
                int best = 0; float bv = sig32(ld_logit[base9 + 3]);
                #pragma unroll
                for (int o = 1; o < 6; ++o) {
                    const float v2 = sig32(ld_logit[base9 + 3 + o]);
                    if (v2 > bv) { bv = v2; best = o; }
                }
                ld_ptr[tid] = best;
                ld_dec[4 * tid] = 0.f; ld_dec[4 * tid + 1] = 0.f; ld_dec[4 * tid + 2] = 1.f;
            }
            __syncthreads();
            // ctx[j] += encoded[batch_j, ptr_j, :] at own column t
            #pragma unroll
            for (int j = 0; j < 4; ++j) {
                const float* iseq = input_seq + ((size_t)(gbase + 8 * j) * SEQ + ld_ptr[j]) * 3;
                ctx[j] += fmaf(iseq[0], w0, fmaf(iseq[1], w1, fmaf(iseq[2], w2, inb_t)));
            }
            // ================= head #2 (post-ctx-update) =================
            {
                float hq[36];
                #pragma unroll
                for (int j = 0; j < 4; ++j) {
                    const float v = xn[j] + ctx[j];
                    #pragma unroll
                    for (int o = 0; o < ODIM; ++o) hq[j * ODIM + o] = v * hw[o];
                }
                #pragma unroll
                for (int m = 1; m < 64; m <<= 1)
                    #pragma unroll
                    for (int u = 0; u < 36; ++u) hq[u] += __shfl_xor(hq[u], m);
                if ((tid & 63) == 0) {
                    float4* hd = (float4*)&ld_hred[(tid >> 6) * 36];
                    #pragma unroll
                    for (int u = 0; u < 9; ++u)
                        hd[u] = make_float4(hq[4 * u], hq[4 * u + 1], hq[4 * u + 2], hq[4 * u + 3]);
                }
                __syncthreads();
                if (tid < ODIM) {
                    float s = headb[tid];
                    #pragma unroll
                    for (int q = 0; q < 8; ++q) s += ld_hred[q * 36 + mem * ODIM + tid];
                    out[((size_t)b * TSTEPS + i) * ODIM + tid] = sig32(s);
                }
                __syncthreads();
            }
        }
    }
}

extern "C" void kernel_launch(void* const* d_in, const int* in_sizes, int n_in,
                              void* d_out, int out_size, void* d_ws, size_t ws_size,
                              hipStream_t stream) {
    (void)in_sizes; (void)n_in; (void)ws_size; (void)out_size;
    const float* input_seq = (const float*)d_in[0];
    // d_in[1] = autoregressive_steps (scalar) -- T fixed at 63 by the model
    const float* in_W   = (const float*)d_in[2];
    const float* in_b   = (const float*)d_in[3];
    const float* Aarr   = (const float*)d_in[4];
    const float* Barr   = (const float*)d_in[5];
    const float* Carr   = (const float*)d_in[6];
    const float* Darr   = (const float*)d_in[7];
    const float* outW   = (const float*)d_in[8];
    const float* outb   = (const float*)d_in[9];
    const float* ln_g   = (const float*)d_in[10];
    const float* ln_b   = (const float*)d_in[11];
    const float* headW  = (const float*)d_in[12];
    const float* headb  = (const float*)d_in[13];
    float* out = (float*)d_out;

    // ws layout: fg [0,1K) (legacy, unused), fz [1K,2K), fx [2K,3K), xid [3K,4K),
    // zws [4K, 4K+2MB): 64 groups x [mem][batch][512] partials
    unsigned* fz  = (unsigned*)d_ws + BATCH;
    unsigned* fx  = (unsigned*)d_ws + 2 * BATCH;
    unsigned* xid = (unsigned*)d_ws + 3 * BATCH;
    float* zws = (float*)((char*)d_ws + 4096);

    // zero all flags every launch (ws is poisoned 0xAA by the harness)
    hipMemsetAsync(d_ws, 0, 4096, stream);

    s4_decode_kernel<<<BATCH, NTHR, 0, stream>>>(
        input_seq, in_W, in_b, Aarr, Barr, Carr, Darr,
        outW, outb, ln_g, ln_b, headW, headb, out,
        zws, fz, fx, xid);
}

// Round 4
// 1881.590 us; speedup vs baseline: 1.5442x; 1.5094x over previous
//
#include <hip/hip_runtime.h>
#include <math.h>

// Problem constants (fixed by the reference)
#define HDIM   512
#define NDIM   16
#define SEQ    64
#define TSTEPS 63
#define BATCH  256
#define ODIM   9
#define NTHR   512

// R11: ZERO inter-WG communication. R9/R10's one-rendezvous group design
// regressed 2x with a layout-independent 4.2GB FETCH that two rounds of
// theory failed to explain -> abandon the mechanism. One WG = one batch:
// each WG computes the FULL 512x512 matvec for its batch, streaming the
// 1MB per-blk weight matrix from L2 each blk-step. Weights (2MB) are shared
// by all 32 WGs/XCD -> L2-resident; per-CU stream 1MB/blk-step @ ~56B/cyc
// ~= 7us -> ~1.0-1.15ms predicted total. No mailbox, no flags, no XCD
// assumptions, no spin loops (no hang class, no fabric mystery).
// Register budget: blk0 A/B/C in VGPRs (48), blk1 A/B/C staged in LDS
// (96KB, <=2-way bank aliasing = free), D in LDS. __launch_bounds__(512,1)
// -> 256 VGPR cap, 1 WG/CU by grid (256 WGs on 256 CUs).
// S4 n-reduction: fold-exchange ladder (validated in R9/R10 passing runs):
// 15 shfl, lane n ends holding y for h = hg + 32n -> 1 gelu/lane.

typedef float f32x4 __attribute__((ext_vector_type(4)));

__device__ __forceinline__ float gelu_f32(float x) {
    return 0.5f * x * (1.0f + erff(x * 0.70710678118654752440f));
}

__device__ __forceinline__ float sig32(float x) {
    return 1.0f / (1.0f + expf(-x));
}

__device__ __forceinline__ void fma_row4(float4& acc, const float4 g,
                                         const float4 w0, const float4 w1,
                                         const float4 w2, const float4 w3) {
    acc.x = fmaf(g.w, w3.x, fmaf(g.z, w2.x, fmaf(g.y, w1.x, fmaf(g.x, w0.x, acc.x))));
    acc.y = fmaf(g.w, w3.y, fmaf(g.z, w2.y, fmaf(g.y, w1.y, fmaf(g.x, w0.y, acc.y))));
    acc.z = fmaf(g.w, w3.z, fmaf(g.z, w2.z, fmaf(g.y, w1.z, fmaf(g.x, w0.z, acc.z))));
    acc.w = fmaf(g.w, w3.w, fmaf(g.z, w2.w, fmaf(g.y, w1.w, fmaf(g.x, w0.w, acc.w))));
}

__global__ __launch_bounds__(NTHR, 1)
void s4_decode_kernel(
    const float* __restrict__ input_seq,   // (B,S,3)
    const float* __restrict__ in_W,        // (3,H)
    const float* __restrict__ in_b,        // (H)
    const float* __restrict__ Aarr,        // (L,H,N)
    const float* __restrict__ Barr,        // (L,H,N)
    const float* __restrict__ Carr,        // (L,H,N)
    const float* __restrict__ Darr,        // (L,H)
    const float* __restrict__ outW,        // (L,H,H)
    const float* __restrict__ outb,        // (L,H)
    const float* __restrict__ ln_g,        // (L,H)
    const float* __restrict__ ln_b,        // (L,H)
    const float* __restrict__ headW,       // (H,9)
    const float* __restrict__ headb,       // (9)
    float* __restrict__ out)               // (B,T,9)
{
    __shared__ __align__(16) float ld_x[HDIM];       // block input (dp or xn)
    __shared__ __align__(16) float ld_g[HDIM];       // gelu output
    __shared__ __align__(16) float4 ld_z4[4 * 128];  // 8 KB matvec partials
    __shared__ __align__(16) float ld_A1[HDIM * NDIM];  // 32 KB blk1 params
    __shared__ __align__(16) float ld_B1[HDIM * NDIM];  // 32 KB
    __shared__ __align__(16) float ld_C1[HDIM * NDIM];  // 32 KB
    __shared__ float ld_D0[HDIM];
    __shared__ float ld_D1[HDIM];
    __shared__ float ld_red[16];                     // LN partials (8 waves x 2)
    __shared__ float ld_hred[8 * ODIM];              // head partials
    __shared__ float ld_logit[ODIM + 1];
    __shared__ float ld_dec[4];
    __shared__ int   ld_ptr;

    const int b   = blockIdx.x;
    const int tid = threadIdx.x;
    const int n   = tid & 15;               // state n-index
    const int hg  = tid >> 4;               // [0,32) h sub-position

    // ---- stage blk1 A/B/C + D into LDS (one-time) ----
    for (int idx = tid; idx < HDIM * NDIM; idx += NTHR) {
        ld_A1[idx] = Aarr[HDIM * NDIM + idx];
        ld_B1[idx] = Barr[HDIM * NDIM + idx];
        ld_C1[idx] = Carr[HDIM * NDIM + idx];
    }
    ld_D0[tid] = Darr[tid];
    ld_D1[tid] = Darr[HDIM + tid];

    // ---- persistent: blk0 params + both blk states in registers ----
    float s0[16], s1[16];
    float A0[16], B0[16], C0[16];
    #pragma unroll
    for (int k = 0; k < 16; ++k) {
        const int h  = hg + 32 * k;
        const int i0 = h * NDIM + n;
        A0[k] = Aarr[i0]; B0[k] = Barr[i0]; C0[k] = Carr[i0];
        s0[k] = 0.f; s1[k] = 0.f;
    }

    // per-column constants
    const float inb_t = in_b[tid];
    const float w0 = in_W[tid], w1 = in_W[HDIM + tid], w2 = in_W[2 * HDIM + tid];
    const float ob0 = outb[tid], ob1 = outb[HDIM + tid];
    const float lg0 = ln_g[tid], lg1 = ln_g[HDIM + tid];
    const float lb0 = ln_b[tid], lb1 = ln_b[HDIM + tid];
    float hw[ODIM];
    #pragma unroll
    for (int o = 0; o < ODIM; ++o) hw[o] = headW[tid * ODIM + o];

    float ctx = 0.f;
    if (tid == 0) { ld_dec[0] = 0.f; ld_dec[1] = 0.f; ld_dec[2] = 1.f; }
    __syncthreads();

    for (int i = 0; i < TSTEPS; ++i) {
        // ---- decoder input projection ----
        const float dpv = fmaf(ld_dec[0], w0,
                          fmaf(ld_dec[1], w1,
                          fmaf(ld_dec[2], w2, inb_t)));
        __syncthreads();                    // ld_dec consumed
        ld_x[tid] = dpv;
        __syncthreads();

        float xn = 0.f;

        #pragma unroll
        for (int blk = 0; blk < 2; ++blk) {
            // ---- S4 state update + C*s partials ----
            float p[16];
            if (blk == 0) {
                #pragma unroll
                for (int k = 0; k < 16; ++k) {
                    const float x  = ld_x[hg + 32 * k];
                    const float sv = fmaf(A0[k], s0[k], B0[k] * x);
                    s0[k] = sv;
                    p[k] = sv * C0[k];
                }
            } else {
                #pragma unroll
                for (int k = 0; k < 16; ++k) {
                    const int ia = (hg + 32 * k) * NDIM + n;
                    const float x  = ld_x[hg + 32 * k];
                    const float sv = fmaf(ld_A1[ia], s1[k], ld_B1[ia] * x);
                    s1[k] = sv;
                    p[k] = sv * ld_C1[ia];
                }
            }
            // ---- fold-exchange reduce over n (16 lanes, 16 values):
            //      lane n ends holding full sum of value v == n
            {
                float q8[8];
                { const bool bt = (n & 1) != 0;
                  #pragma unroll
                  for (int u = 0; u < 8; ++u) {
                      const float sd = bt ? p[2 * u] : p[2 * u + 1];
                      const float rc = __shfl_xor(sd, 1);
                      q8[u] = (bt ? p[2 * u + 1] : p[2 * u]) + rc;
                  } }
                float q4[4];
                { const bool bt = (n & 2) != 0;
                  #pragma unroll
                  for (int u = 0; u < 4; ++u) {
                      const float sd = bt ? q8[2 * u] : q8[2 * u + 1];
                      const float rc = __shfl_xor(sd, 2);
                      q4[u] = (bt ? q8[2 * u + 1] : q8[2 * u]) + rc;
                  } }
                float q2[2];
                { const bool bt = (n & 4) != 0;
                  #pragma unroll
                  for (int u = 0; u < 2; ++u) {
                      const float sd = bt ? q2[0] * 0.f + (bt ? q4[2 * u] : q4[2 * u + 1]) : q4[2 * u + 1];
                      // (expanded below for clarity)
                      q2[u] = 0.f; (void)sd;
                  } }
                // -- rewritten stage 3 & 4 without the botched line above --
                { const bool bt = (n & 4) != 0;
                  #pragma unroll
                  for (int u = 0; u < 2; ++u) {
                      const float sd = bt ? q4[2 * u] : q4[2 * u + 1];
                      const float rc = __shfl_xor(sd, 4);
                      q2[u] = (bt ? q4[2 * u + 1] : q4[2 * u]) + rc;
                  } }
                float y;
                { const bool bt = (n & 8) != 0;
                  const float sd = bt ? q2[0] : q2[1];
                  const float rc = __shfl_xor(sd, 8);
                  y = (bt ? q2[1] : q2[0]) + rc; }
                // lane n holds y for h = hg + 32n
                const int h2 = hg + 32 * n;
                const float dd = blk ? ld_D1[h2] : ld_D0[h2];
                ld_g[h2] = gelu_f32(fmaf(dd, ld_x[h2], y));
            }
            __syncthreads();

            // ---- full matvec: 512 rows x 512 outputs, rows split 4 ways ----
            {
                const int rg = tid >> 7;            // row quarter [0,4)
                const int c  = tid & 127;           // float4 output column
                const float4* Wb = (const float4*)outW
                    + (((size_t)blk) << 16) + (size_t)(rg * 128) * 128 + c;
                const float* gq = &ld_g[rg * 128];
                float4 acc = make_float4(0.f, 0.f, 0.f, 0.f);
                float4 a0 = Wb[0 * 128], a1 = Wb[1 * 128],
                       a2 = Wb[2 * 128], a3 = Wb[3 * 128];
                #pragma unroll 2
                for (int rr = 0; rr < 128; rr += 4) {
                    float4 b0, b1, b2, b3;
                    if (rr < 124) {
                        b0 = Wb[(size_t)(rr + 4) * 128];
                        b1 = Wb[(size_t)(rr + 5) * 128];
                        b2 = Wb[(size_t)(rr + 6) * 128];
                        b3 = Wb[(size_t)(rr + 7) * 128];
                    }
                    const float4 g4 = *(const float4*)&gq[rr];
                    fma_row4(acc, g4, a0, a1, a2, a3);
                    if (rr < 124) { a0 = b0; a1 = b1; a2 = b2; a3 = b3; }
                }
                ld_z4[rg * 128 + c] = acc;
            }
            __syncthreads();

            // ---- combine 4 row-quarter partials + residual + one-pass LN ----
            {
                const float* zf = (const float*)ld_z4;
                const float z = zf[0 * HDIM + tid] + zf[1 * HDIM + tid]
                              + zf[2 * HDIM + tid] + zf[3 * HDIM + tid]
                              + (blk ? ob1 : ob0);
                const float res = (i == 0) ? dpv : z;   // ref: residual=proj @ i==0
                const float tmp = z + res;
                float v1 = tmp, v2 = tmp * tmp;
                #pragma unroll
                for (int m = 1; m < 64; m <<= 1) {
                    v1 += __shfl_xor(v1, m);
                    v2 += __shfl_xor(v2, m);
                }
                if ((tid & 63) == 0) {
                    ld_red[2 * (tid >> 6)]     = v1;
                    ld_red[2 * (tid >> 6) + 1] = v2;
                }
                __syncthreads();
                float s1r = 0.f, s2r = 0.f;
                #pragma unroll
                for (int q = 0; q < 8; ++q) { s1r += ld_red[2 * q]; s2r += ld_red[2 * q + 1]; }
                const float mu  = s1r * (1.f / 512.f);
                const float var = s2r * (1.f / 512.f) - mu * mu;
                const float rs  = rsqrtf(var + 1e-5f);
                xn = (tmp - mu) * rs * (blk ? lg1 : lg0) + (blk ? lb1 : lb0);
                __syncthreads();            // ld_red consumed; ld_x safe to overwrite
                if (blk == 0) {
                    ld_x[tid] = xn;
                    __syncthreads();
                }
            }
        } // blk

        // ================= head #1 =================
        {
            const float v = xn + ctx;
            float hp[ODIM];
            #pragma unroll
            for (int o = 0; o < ODIM; ++o) hp[o] = v * hw[o];
            #pragma unroll
            for (int m = 1; m < 64; m <<= 1) {
                #pragma unroll
                for (int o = 0; o < ODIM; ++o) hp[o] += __shfl_xor(hp[o], m);
            }
            if ((tid & 63) == 0) {
                const int wv = tid >> 6;
                #pragma unroll
                for (int o = 0; o < ODIM; ++o) ld_hred[wv * ODIM + o] = hp[o];
            }
            __syncthreads();
            if (tid < ODIM) {
                float s = headb[tid];
                #pragma unroll
                for (int wv = 0; wv < 8; ++wv) s += ld_hred[wv * ODIM + tid];
                ld_logit[tid] = s;
            }
            __syncthreads();
        }

        const bool is_out = ((i & 1) == 0);
        if (is_out) {
            if (tid < ODIM)
                out[((size_t)b * TSTEPS + i) * ODIM + tid] = sig32(ld_logit[tid]);
            if (tid == 0) {
                const float nc = (sig32(ld_logit[0]) > 0.5f) ? 1.f : 0.f;
                ld_dec[0] = nc; ld_dec[1] = 1.f; ld_dec[2] = 0.f;
            }
            __syncthreads();
        } else {
            // np.argmax over f32 SIGMOIDS (saturation => not logit-argmax!)
            if (tid == 0) {
                int best = 0; float bv = sig32(ld_logit[3]);
                #pragma unroll
                for (int o = 1; o < 6; ++o) {
                    const float v2 = sig32(ld_logit[3 + o]);
                    if (v2 > bv) { bv = v2; best = o; }
                }
                ld_ptr = best;
                ld_dec[0] = 0.f; ld_dec[1] = 0.f; ld_dec[2] = 1.f;
            }
            __syncthreads();
            {   // ctx += encoded[b, ptr, :] at own column t
                const float* iseq = input_seq + ((size_t)b * SEQ + ld_ptr) * 3;
                ctx += fmaf(iseq[0], w0, fmaf(iseq[1], w1, fmaf(iseq[2], w2, inb_t)));
            }
            __syncthreads();
            // ================= head #2 (post-ctx-update) =================
            {
                const float v = xn + ctx;
                float hq[ODIM];
                #pragma unroll
                for (int o = 0; o < ODIM; ++o) hq[o] = v * hw[o];
                #pragma unroll
                for (int m = 1; m < 64; m <<= 1) {
                    #pragma unroll
                    for (int o = 0; o < ODIM; ++o) hq[o] += __shfl_xor(hq[o], m);
                }
                if ((tid & 63) == 0) {
                    const int wv = tid >> 6;
                    #pragma unroll
                    for (int o = 0; o < ODIM; ++o) ld_hred[wv * ODIM + o] = hq[o];
                }
                __syncthreads();
                if (tid < ODIM) {
                    float s = headb[tid];
                    #pragma unroll
                    for (int wv = 0; wv < 8; ++wv) s += ld_hred[wv * ODIM + tid];
                    out[((size_t)b * TSTEPS + i) * ODIM + tid] = sig32(s);
                }
                __syncthreads();
            }
        }
    }
}

extern "C" void kernel_launch(void* const* d_in, const int* in_sizes, int n_in,
                              void* d_out, int out_size, void* d_ws, size_t ws_size,
                              hipStream_t stream) {
    (void)in_sizes; (void)n_in; (void)d_ws; (void)ws_size; (void)out_size;
    const float* input_seq = (const float*)d_in[0];
    // d_in[1] = autoregressive_steps (scalar) -- T fixed at 63 by the model
    const float* in_W   = (const float*)d_in[2];
    const float* in_b   = (const float*)d_in[3];
    const float* Aarr   = (const float*)d_in[4];
    const float* Barr   = (const float*)d_in[5];
    const float* Carr   = (const float*)d_in[6];
    const float* Darr   = (const float*)d_in[7];
    const float* outW   = (const float*)d_in[8];
    const float* outb   = (const float*)d_in[9];
    const float* ln_g   = (const float*)d_in[10];
    const float* ln_b   = (const float*)d_in[11];
    const float* headW  = (const float*)d_in[12];
    const float* headb  = (const float*)d_in[13];
    float* out = (float*)d_out;

    // No workspace use: zero inter-WG communication in this design.
    s4_decode_kernel<<<BATCH, NTHR, 0, stream>>>(
        input_seq, in_W, in_b, Aarr, Barr, Carr, Darr,
        outW, outb, ln_g, ln_b, headW, headb, out);
}